// Round 10
// baseline (440.130 us; speedup 1.0000x reference)
//
#include <hip/hip_runtime.h>
#include <hip/hip_bf16.h>
#include <stdint.h>

typedef uint16_t u16;
typedef __attribute__((ext_vector_type(8))) short bf16x8;
typedef __attribute__((ext_vector_type(4))) float f32x4;

#define DEVI static __device__ __forceinline__
#define GLOAD_LDS(gptr, lptr) \
  __builtin_amdgcn_global_load_lds((const __attribute__((address_space(1))) void*)(gptr), \
                                   (__attribute__((address_space(3))) void*)(lptr), 16, 0, 0)

constexpr int Bc = 4, Sc = 1024, Hc = 1024, NHc = 16, HDc = 64;
constexpr int Mrows = Bc * Sc; // 4096

DEVI u16 f2bf(float f) {
  uint32_t u = __builtin_bit_cast(uint32_t, f);
  u += 0x7FFFu + ((u >> 16) & 1u);
  return (u16)(u >> 16);
}
DEVI float bf2f(u16 x) { return __builtin_bit_cast(float, (uint32_t)x << 16); }

DEVI f32x4 mfma16(bf16x8 a, bf16x8 b, f32x4 c) {
  return __builtin_amdgcn_mfma_f32_16x16x32_bf16(a, b, c, 0, 0, 0);
}

// ---------------- batched f32 -> bf16 conversion ----------------
struct CV { const float* in[6]; u16* out[6]; };

__global__ __launch_bounds__(256) void cvtN_kernel(CV a, int n8) {
  int z = blockIdx.z;
  int i = blockIdx.x * 256 + threadIdx.x;
  if (i >= n8) return;
  const f32x4* p = (const f32x4*)(a.in[z] + (size_t)i * 8);
  f32x4 x = p[0], y = p[1];
  union { bf16x8 v; u16 s[8]; } r;
#pragma unroll
  for (int j = 0; j < 4; ++j) { r.s[j] = f2bf(x[j]); r.s[4 + j] = f2bf(y[j]); }
  *(bf16x8*)(a.out[z] + (size_t)i * 8) = r.v;
}

// ---------------- mask int32 -> bitmask ----------------
__global__ __launch_bounds__(256) void maskpack_kernel(const int* __restrict__ mask,
                                                       uint32_t* __restrict__ out) {
  int i = blockIdx.x * 256 + threadIdx.x;
  const int4* p = (const int4*)(mask + (size_t)i * 32);
  uint32_t r = 0;
#pragma unroll
  for (int j = 0; j < 8; ++j) {
    int4 v = p[j];
    uint32_t nib = (v.x ? 1u : 0u) | (v.y ? 2u : 0u) | (v.z ? 4u : 0u) | (v.w ? 8u : 0u);
    r |= nib << (j * 4);
  }
  out[i] = r;
}

// ---------------- fused 5-way projection GEMM ----------------
struct P5 { const u16* A[5]; const u16* W[5]; const float* b[5]; u16* o[5]; };

__global__ __launch_bounds__(256) void proj5_kernel(P5 args) {
  constexpr int K = 1024, BK = 32;
  __shared__ u16 As[128 * BK];
  __shared__ u16 Bs[128 * BK];
  const int z = blockIdx.z;
  const u16* __restrict__ A = args.A[z];
  const u16* __restrict__ Bw = args.W[z];
  const float* __restrict__ bias = args.b[z];
  u16* __restrict__ Cout = args.o[z];
  const int t = threadIdx.x;
  const int w = t >> 6, l = t & 63;
  const int lr = l & 15, lh = l >> 4;
  const int m0 = blockIdx.y * 128, n0 = blockIdx.x * 128;
  const int wr = w >> 1, wc = w & 1;
  f32x4 acc[4][4] = {};

  const int row_s = t >> 2, k8 = (t & 3) << 3;
  const u16* ga = A + (size_t)(m0 + row_s) * K + k8;
  const u16* gb = Bw + (size_t)(n0 + row_s) * K + k8;

  for (int kt = 0; kt < K; kt += BK) {
    GLOAD_LDS(ga + kt, As + t * 8);
    GLOAD_LDS(ga + (size_t)64 * K + kt, As + 2048 + t * 8);
    GLOAD_LDS(gb + kt, Bs + t * 8);
    GLOAD_LDS(gb + (size_t)64 * K + kt, Bs + 2048 + t * 8);
    __syncthreads();
    bf16x8 af[4], bfr[4];
#pragma unroll
    for (int mi = 0; mi < 4; ++mi)
      af[mi] = *(const bf16x8*)(As + (wr * 64 + mi * 16 + lr) * BK + lh * 8);
#pragma unroll
    for (int ni = 0; ni < 4; ++ni)
      bfr[ni] = *(const bf16x8*)(Bs + (wc * 64 + ni * 16 + lr) * BK + lh * 8);
#pragma unroll
    for (int mi = 0; mi < 4; ++mi)
#pragma unroll
      for (int ni = 0; ni < 4; ++ni)
        acc[mi][ni] = mfma16(af[mi], bfr[ni], acc[mi][ni]);
    __syncthreads();
  }

#pragma unroll
  for (int mi = 0; mi < 4; ++mi) {
#pragma unroll
    for (int ni = 0; ni < 4; ++ni) {
      int col = n0 + wc * 64 + ni * 16 + lr;
      float bc = bias[col];
      int hcol = col >> 6, dcol = col & 63;
      int rbase = m0 + wr * 64 + mi * 16 + lh * 4;
      int bb = rbase >> 10, sb = rbase & 1023;
      if (z == 4) {
        ushort4 pk;
        pk.x = f2bf(acc[mi][ni][0] + bc);
        pk.y = f2bf(acc[mi][ni][1] + bc);
        pk.z = f2bf(acc[mi][ni][2] + bc);
        pk.w = f2bf(acc[mi][ni][3] + bc);
        *(ushort4*)&Cout[((size_t)(bb * NHc + hcol) * HDc + dcol) * Sc + sb] = pk;
      } else {
#pragma unroll
        for (int r = 0; r < 4; ++r)
          Cout[((size_t)(bb * NHc + hcol) * Sc + (sb + r)) * HDc + dcol] =
              f2bf(acc[mi][ni][r] + bc);
      }
    }
  }
}

// ---------------- output projection GEMM (f32 out, [M,N]) ----------------
__global__ __launch_bounds__(256) void gemmo_kernel(const u16* __restrict__ A,
                                                    const u16* __restrict__ Bw,
                                                    const float* __restrict__ bias,
                                                    float* __restrict__ Cout) {
  constexpr int K = 1024, N = 1024, BK = 32;
  __shared__ u16 As[128 * BK];
  __shared__ u16 Bs[128 * BK];
  const int t = threadIdx.x;
  const int w = t >> 6, l = t & 63;
  const int lr = l & 15, lh = l >> 4;
  const int m0 = blockIdx.y * 128, n0 = blockIdx.x * 128;
  const int wr = w >> 1, wc = w & 1;
  f32x4 acc[4][4] = {};

  const int row_s = t >> 2, k8 = (t & 3) << 3;
  const u16* ga = A + (size_t)(m0 + row_s) * K + k8;
  const u16* gb = Bw + (size_t)(n0 + row_s) * K + k8;

  for (int kt = 0; kt < K; kt += BK) {
    GLOAD_LDS(ga + kt, As + t * 8);
    GLOAD_LDS(ga + (size_t)64 * K + kt, As + 2048 + t * 8);
    GLOAD_LDS(gb + kt, Bs + t * 8);
    GLOAD_LDS(gb + (size_t)64 * K + kt, Bs + 2048 + t * 8);
    __syncthreads();
    bf16x8 af[4], bfr[4];
#pragma unroll
    for (int mi = 0; mi < 4; ++mi)
      af[mi] = *(const bf16x8*)(As + (wr * 64 + mi * 16 + lr) * BK + lh * 8);
#pragma unroll
    for (int ni = 0; ni < 4; ++ni)
      bfr[ni] = *(const bf16x8*)(Bs + (wc * 64 + ni * 16 + lr) * BK + lh * 8);
#pragma unroll
    for (int mi = 0; mi < 4; ++mi)
#pragma unroll
      for (int ni = 0; ni < 4; ++ni)
        acc[mi][ni] = mfma16(af[mi], bfr[ni], acc[mi][ni]);
    __syncthreads();
  }

#pragma unroll
  for (int mi = 0; mi < 4; ++mi) {
#pragma unroll
    for (int ni = 0; ni < 4; ++ni) {
      int col = n0 + wc * 64 + ni * 16 + lr;
      float bc = bias[col];
#pragma unroll
      for (int r = 0; r < 4; ++r) {
        int rowg = m0 + wr * 64 + mi * 16 + lh * 4 + r;
        Cout[(size_t)rowg * N + col] = acc[mi][ni][r] + bc;
      }
    }
  }
}

// ---------------- phase A: energy + select + softmax -> P (f32, normalized) --
// Swapped QK^T (A=K, B=Q): lane holds P[q=q0+lr][k = w*256 + kt*16 + lh*4 + r].
// P in f32 registers end-to-end; single-barrier cross-wave softmax combine.
// Stores issued at kernel end; no barrier behind them (drain overlaps blocks).
__global__ __launch_bounds__(256, 3) void esm_kernel(const u16* __restrict__ Qh,
                                                     const u16* __restrict__ Kh,
                                                     const u16* __restrict__ Qsh,
                                                     const u16* __restrict__ Ksh,
                                                     const uint32_t* __restrict__ mbits,
                                                     float* __restrict__ Pout) {
  __shared__ float redM[4][16];
  __shared__ float redS[4][16];
  const int t = threadIdx.x, w = t >> 6, l = t & 63;
  const int lr = l & 15, lh = l >> 4;
  // XCD-aware remap: 64 q-tiles of one head stay on one XCD
  int lid = blockIdx.y * 64 + blockIdx.x;
  int xcd = lid & 7, j = lid >> 3;
  int bh = xcd * 8 + (j >> 6);
  int q0 = (j & 63) << 4;
  const int b = bh >> 4;
  const size_t hoff = (size_t)bh * Sc * HDc;

  const u16* Qp = Qh + hoff + (size_t)(q0 + lr) * HDc + lh * 8;
  const u16* Qsp = Qsh + hoff + (size_t)(q0 + lr) * HDc + lh * 8;
  bf16x8 qf0 = *(const bf16x8*)Qp, qf1 = *(const bf16x8*)(Qp + 32);
  bf16x8 sf0 = *(const bf16x8*)Qsp, sf1 = *(const bf16x8*)(Qsp + 32);

  uint32_t mwreg[8];
  {
    const uint32_t* mrow_l = mbits + ((size_t)b * Sc + q0 + lr) * 32 + w * 8;
    *(uint4*)&mwreg[0] = *(const uint4*)mrow_l;
    *(uint4*)&mwreg[4] = *(const uint4*)(mrow_l + 4);
  }

  const u16* Kbase = Kh + hoff + (size_t)((w << 8) + lr) * HDc + lh * 8;
  const u16* Ksbase = Ksh + hoff + (size_t)((w << 8) + lr) * HDc + lh * 8;

  bf16x8 ka[3], kb[3], sa[3], sb[3];
#define LOADK(slot, it) do { \
    const u16* Kp_ = Kbase + (it) * (16 * HDc); \
    const u16* Sp_ = Ksbase + (it) * (16 * HDc); \
    ka[slot] = *(const bf16x8*)Kp_;  kb[slot] = *(const bf16x8*)(Kp_ + 32); \
    sa[slot] = *(const bf16x8*)Sp_;  sb[slot] = *(const bf16x8*)(Sp_ + 32); } while (0)

  LOADK(0, 0); LOADK(1, 1); LOADK(2, 2);

  f32x4 p[16];
#pragma unroll
  for (int kt = 0; kt < 16; ++kt) {
    const int s = kt % 3;
    f32x4 e = {}, es = {};
    e = mfma16(ka[s], qf0, e);
    e = mfma16(kb[s], qf1, e);
    es = mfma16(sa[s], sf0, es);
    es = mfma16(sb[s], sf1, es);
    if (kt + 3 < 16) LOADK(s, kt + 3);
    uint32_t md = mwreg[kt >> 1];
    int sh = ((kt & 1) << 4) + (lh << 2);
    f32x4 r;
    r[0] = ((md >> (sh + 0)) & 1u ? es[0] : e[0]) * 0.125f;
    r[1] = ((md >> (sh + 1)) & 1u ? es[1] : e[1]) * 0.125f;
    r[2] = ((md >> (sh + 2)) & 1u ? es[2] : e[2]) * 0.125f;
    r[3] = ((md >> (sh + 3)) & 1u ? es[3] : e[3]) * 0.125f;
    p[kt] = r;
  }
#undef LOADK

  // wave-local stats
  float mw = -1e30f;
#pragma unroll
  for (int kt = 0; kt < 16; ++kt)
    mw = fmaxf(mw, fmaxf(fmaxf(p[kt][0], p[kt][1]), fmaxf(p[kt][2], p[kt][3])));
  mw = fmaxf(mw, __shfl_xor(mw, 16));
  mw = fmaxf(mw, __shfl_xor(mw, 32));
  float sw = 0.f;
#pragma unroll
  for (int kt = 0; kt < 16; ++kt) {
#pragma unroll
    for (int i = 0; i < 4; ++i) { float tt = __expf(p[kt][i] - mw); p[kt][i] = tt; sw += tt; }
  }
  sw += __shfl_xor(sw, 16);
  sw += __shfl_xor(sw, 32);
  if (lh == 0) { redM[w][lr] = mw; redS[w][lr] = sw; }
  __syncthreads();

  float m0_ = redM[0][lr], m1_ = redM[1][lr], m2_ = redM[2][lr], m3_ = redM[3][lr];
  float gm = fmaxf(fmaxf(m0_, m1_), fmaxf(m2_, m3_));
  float gsum = redS[0][lr] * __expf(m0_ - gm) + redS[1][lr] * __expf(m1_ - gm) +
               redS[2][lr] * __expf(m2_ - gm) + redS[3][lr] * __expf(m3_ - gm);
  const float scale = __expf(mw - gm) / gsum;

  float* Prow = Pout + ((size_t)bh * Sc + q0 + lr) * Sc + (w << 8) + (lh << 2);
#pragma unroll
  for (int kt = 0; kt < 16; ++kt) {
    f32x4 pv = p[kt] * scale;
    *(f32x4*)(Prow + (kt << 4)) = pv;
  }
}

// ---------------- phase B: PV = P (f32, from d_out) x Vth -> ctx ------------
// 64 q-rows per block (wave w -> q [q0+w*16, +16)), all 64 d per wave.
// P streamed as f32x4 pairs, converted to bf16 A-frags in-register.
__global__ __launch_bounds__(256, 4) void pv2_kernel(const float* __restrict__ P,
                                                     const u16* __restrict__ Vt,
                                                     u16* __restrict__ ctx) {
  const int t = threadIdx.x, w = t >> 6, l = t & 63;
  const int lr = l & 15, lh = l >> 4;
  const int bh = blockIdx.y, b = bh >> 4, h = bh & 15;
  const int q0 = (blockIdx.x << 6) + (w << 4);
  const float* Pr = P + ((size_t)bh * Sc + q0 + lr) * Sc + lh * 8;
  const u16* Vb = Vt + ((size_t)bh * HDc + lr) * Sc + lh * 8;
  f32x4 acc[4] = {};
#pragma unroll
  for (int k0 = 0; k0 < Sc; k0 += 32) {
    f32x4 p0 = *(const f32x4*)(Pr + k0);
    f32x4 p1 = *(const f32x4*)(Pr + k0 + 4);
    union { bf16x8 v; u16 s[8]; } a;
#pragma unroll
    for (int i = 0; i < 4; ++i) { a.s[i] = f2bf(p0[i]); a.s[4 + i] = f2bf(p1[i]); }
#pragma unroll
    for (int dn = 0; dn < 4; ++dn) {
      bf16x8 bv = *(const bf16x8*)(Vb + (size_t)(dn * 16) * Sc + k0);
      acc[dn] = mfma16(a.v, bv, acc[dn]);
    }
  }
#pragma unroll
  for (int dn = 0; dn < 4; ++dn) {
    int d = dn * 16 + lr;
#pragma unroll
    for (int r = 0; r < 4; ++r) {
      int row = q0 + (lh << 2) + r;
      ctx[((size_t)b * Sc + row) * Hc + (h << 6) + d] = f2bf(acc[dn][r]);
    }
  }
}

extern "C" void kernel_launch(void* const* d_in, const int* in_sizes, int n_in,
                              void* d_out, int out_size, void* d_ws, size_t ws_size,
                              hipStream_t stream) {
  const float* fin[5] = { (const float*)d_in[0], (const float*)d_in[1], (const float*)d_in[2],
                          (const float*)d_in[3], (const float*)d_in[4] };
  const int* mask = (const int*)d_in[5];
  const float* W[6] = { (const float*)d_in[6], (const float*)d_in[8], (const float*)d_in[10],
                        (const float*)d_in[12], (const float*)d_in[14], (const float*)d_in[16] };
  const float* bias[6] = { (const float*)d_in[7], (const float*)d_in[9], (const float*)d_in[11],
                           (const float*)d_in[13], (const float*)d_in[15], (const float*)d_in[17] };

  float* out_x = (float*)d_out;
  float* out_attn = out_x + (size_t)Bc * Sc * Hc;

  const size_t NE = (size_t)Bc * Sc * Hc; // 4M elems
  const size_t NW = (size_t)Hc * Hc;      // 1M elems
  u16* p = (u16*)d_ws;
  u16* xin[5]; for (int i = 0; i < 5; ++i) { xin[i] = p; p += NE; }
  u16* wbf[6]; for (int i = 0; i < 6; ++i) { wbf[i] = p; p += NW; }
  u16* Qh  = p; p += NE;
  u16* Kh  = p; p += NE;
  u16* Qsh = p; p += NE;
  u16* Ksh = p; p += NE;
  u16* Vth = p; p += NE;
  u16* ctx = p; p += NE;
  uint32_t* mbits = (uint32_t*)xin[0]; // reused after proj5

  {
    CV a{};
    for (int i = 0; i < 5; ++i) { a.in[i] = fin[i]; a.out[i] = xin[i]; }
    cvtN_kernel<<<dim3((int)(NE / 8 / 256), 1, 5), 256, 0, stream>>>(a, (int)(NE / 8));
  }
  {
    CV a{};
    for (int i = 0; i < 6; ++i) { a.in[i] = W[i]; a.out[i] = wbf[i]; }
    cvtN_kernel<<<dim3((int)(NW / 8 / 256), 1, 6), 256, 0, stream>>>(a, (int)(NW / 8));
  }

  P5 args;
  u16* projout[5] = { Qh, Kh, Qsh, Ksh, Vth };
  for (int i = 0; i < 5; ++i) { args.A[i] = xin[i]; args.W[i] = wbf[i]; args.b[i] = bias[i]; args.o[i] = projout[i]; }
  proj5_kernel<<<dim3(Hc / 128, Mrows / 128, 5), 256, 0, stream>>>(args);

  maskpack_kernel<<<(int)((size_t)Bc * Sc * Sc / 32 / 256), 256, 0, stream>>>(mask, mbits);

  esm_kernel<<<dim3(Sc / 16, Bc * NHc), 256, 0, stream>>>(Qh, Kh, Qsh, Ksh, mbits, out_attn);

  pv2_kernel<<<dim3(Sc / 64, Bc * NHc), 256, 0, stream>>>(out_attn, Vth, ctx);

  gemmo_kernel<<<dim3(Hc / 128, Mrows / 128), 256, 0, stream>>>(ctx, wbf[5], bias[5], out_x);
}

// Round 11
// 355.758 us; speedup vs baseline: 1.2372x; 1.2372x over previous
//
#include <hip/hip_runtime.h>
#include <hip/hip_bf16.h>
#include <stdint.h>

typedef uint16_t u16;
typedef __attribute__((ext_vector_type(8))) short bf16x8;
typedef __attribute__((ext_vector_type(4))) float f32x4;

#define DEVI static __device__ __forceinline__
#define GLOAD_LDS(gptr, lptr) \
  __builtin_amdgcn_global_load_lds((const __attribute__((address_space(1))) void*)(gptr), \
                                   (__attribute__((address_space(3))) void*)(lptr), 16, 0, 0)

constexpr int Bc = 4, Sc = 1024, Hc = 1024, NHc = 16, HDc = 64;
constexpr int Mrows = Bc * Sc; // 4096

DEVI u16 f2bf(float f) {
  uint32_t u = __builtin_bit_cast(uint32_t, f);
  u += 0x7FFFu + ((u >> 16) & 1u);
  return (u16)(u >> 16);
}
DEVI float bf2f(u16 x) { return __builtin_bit_cast(float, (uint32_t)x << 16); }

DEVI f32x4 mfma16(bf16x8 a, bf16x8 b, f32x4 c) {
  return __builtin_amdgcn_mfma_f32_16x16x32_bf16(a, b, c, 0, 0, 0);
}

// ---------------- batched f32 -> bf16 conversion ----------------
struct CV { const float* in[6]; u16* out[6]; };

__global__ __launch_bounds__(256) void cvtN_kernel(CV a, int n8) {
  int z = blockIdx.z;
  int i = blockIdx.x * 256 + threadIdx.x;
  if (i >= n8) return;
  const f32x4* p = (const f32x4*)(a.in[z] + (size_t)i * 8);
  f32x4 x = p[0], y = p[1];
  union { bf16x8 v; u16 s[8]; } r;
#pragma unroll
  for (int j = 0; j < 4; ++j) { r.s[j] = f2bf(x[j]); r.s[4 + j] = f2bf(y[j]); }
  *(bf16x8*)(a.out[z] + (size_t)i * 8) = r.v;
}

// ---------------- mask int32 -> bitmask ----------------
__global__ __launch_bounds__(256) void maskpack_kernel(const int* __restrict__ mask,
                                                       uint32_t* __restrict__ out) {
  int i = blockIdx.x * 256 + threadIdx.x;
  const int4* p = (const int4*)(mask + (size_t)i * 32);
  uint32_t r = 0;
#pragma unroll
  for (int j = 0; j < 8; ++j) {
    int4 v = p[j];
    uint32_t nib = (v.x ? 1u : 0u) | (v.y ? 2u : 0u) | (v.z ? 4u : 0u) | (v.w ? 8u : 0u);
    r |= nib << (j * 4);
  }
  out[i] = r;
}

// ---------------- fused 5-way projection GEMM ----------------
struct P5 { const u16* A[5]; const u16* W[5]; const float* b[5]; u16* o[5]; };

__global__ __launch_bounds__(256) void proj5_kernel(P5 args) {
  constexpr int K = 1024, BK = 32;
  __shared__ u16 As[128 * BK];
  __shared__ u16 Bs[128 * BK];
  const int z = blockIdx.z;
  const u16* __restrict__ A = args.A[z];
  const u16* __restrict__ Bw = args.W[z];
  const float* __restrict__ bias = args.b[z];
  u16* __restrict__ Cout = args.o[z];
  const int t = threadIdx.x;
  const int w = t >> 6, l = t & 63;
  const int lr = l & 15, lh = l >> 4;
  const int m0 = blockIdx.y * 128, n0 = blockIdx.x * 128;
  const int wr = w >> 1, wc = w & 1;
  f32x4 acc[4][4] = {};

  const int row_s = t >> 2, k8 = (t & 3) << 3;
  const u16* ga = A + (size_t)(m0 + row_s) * K + k8;
  const u16* gb = Bw + (size_t)(n0 + row_s) * K + k8;

  for (int kt = 0; kt < K; kt += BK) {
    GLOAD_LDS(ga + kt, As + t * 8);
    GLOAD_LDS(ga + (size_t)64 * K + kt, As + 2048 + t * 8);
    GLOAD_LDS(gb + kt, Bs + t * 8);
    GLOAD_LDS(gb + (size_t)64 * K + kt, Bs + 2048 + t * 8);
    __syncthreads();
    bf16x8 af[4], bfr[4];
#pragma unroll
    for (int mi = 0; mi < 4; ++mi)
      af[mi] = *(const bf16x8*)(As + (wr * 64 + mi * 16 + lr) * BK + lh * 8);
#pragma unroll
    for (int ni = 0; ni < 4; ++ni)
      bfr[ni] = *(const bf16x8*)(Bs + (wc * 64 + ni * 16 + lr) * BK + lh * 8);
#pragma unroll
    for (int mi = 0; mi < 4; ++mi)
#pragma unroll
      for (int ni = 0; ni < 4; ++ni)
        acc[mi][ni] = mfma16(af[mi], bfr[ni], acc[mi][ni]);
    __syncthreads();
  }

#pragma unroll
  for (int mi = 0; mi < 4; ++mi) {
#pragma unroll
    for (int ni = 0; ni < 4; ++ni) {
      int col = n0 + wc * 64 + ni * 16 + lr;
      float bc = bias[col];
      int hcol = col >> 6, dcol = col & 63;
      int rbase = m0 + wr * 64 + mi * 16 + lh * 4;
      int bb = rbase >> 10, sb = rbase & 1023;
      if (z == 4) {
        ushort4 pk;
        pk.x = f2bf(acc[mi][ni][0] + bc);
        pk.y = f2bf(acc[mi][ni][1] + bc);
        pk.z = f2bf(acc[mi][ni][2] + bc);
        pk.w = f2bf(acc[mi][ni][3] + bc);
        *(ushort4*)&Cout[((size_t)(bb * NHc + hcol) * HDc + dcol) * Sc + sb] = pk;
      } else {
#pragma unroll
        for (int r = 0; r < 4; ++r)
          Cout[((size_t)(bb * NHc + hcol) * Sc + (sb + r)) * HDc + dcol] =
              f2bf(acc[mi][ni][r] + bc);
      }
    }
  }
}

// ---------------- output projection GEMM (f32 out, [M,N]) ----------------
__global__ __launch_bounds__(256) void gemmo_kernel(const u16* __restrict__ A,
                                                    const u16* __restrict__ Bw,
                                                    const float* __restrict__ bias,
                                                    float* __restrict__ Cout) {
  constexpr int K = 1024, N = 1024, BK = 32;
  __shared__ u16 As[128 * BK];
  __shared__ u16 Bs[128 * BK];
  const int t = threadIdx.x;
  const int w = t >> 6, l = t & 63;
  const int lr = l & 15, lh = l >> 4;
  const int m0 = blockIdx.y * 128, n0 = blockIdx.x * 128;
  const int wr = w >> 1, wc = w & 1;
  f32x4 acc[4][4] = {};

  const int row_s = t >> 2, k8 = (t & 3) << 3;
  const u16* ga = A + (size_t)(m0 + row_s) * K + k8;
  const u16* gb = Bw + (size_t)(n0 + row_s) * K + k8;

  for (int kt = 0; kt < K; kt += BK) {
    GLOAD_LDS(ga + kt, As + t * 8);
    GLOAD_LDS(ga + (size_t)64 * K + kt, As + 2048 + t * 8);
    GLOAD_LDS(gb + kt, Bs + t * 8);
    GLOAD_LDS(gb + (size_t)64 * K + kt, Bs + 2048 + t * 8);
    __syncthreads();
    bf16x8 af[4], bfr[4];
#pragma unroll
    for (int mi = 0; mi < 4; ++mi)
      af[mi] = *(const bf16x8*)(As + (wr * 64 + mi * 16 + lr) * BK + lh * 8);
#pragma unroll
    for (int ni = 0; ni < 4; ++ni)
      bfr[ni] = *(const bf16x8*)(Bs + (wc * 64 + ni * 16 + lr) * BK + lh * 8);
#pragma unroll
    for (int mi = 0; mi < 4; ++mi)
#pragma unroll
      for (int ni = 0; ni < 4; ++ni)
        acc[mi][ni] = mfma16(af[mi], bfr[ni], acc[mi][ni]);
    __syncthreads();
  }

#pragma unroll
  for (int mi = 0; mi < 4; ++mi) {
#pragma unroll
    for (int ni = 0; ni < 4; ++ni) {
      int col = n0 + wc * 64 + ni * 16 + lr;
      float bc = bias[col];
#pragma unroll
      for (int r = 0; r < 4; ++r) {
        int rowg = m0 + wr * 64 + mi * 16 + lh * 4 + r;
        Cout[(size_t)rowg * N + col] = acc[mi][ni][r] + bc;
      }
    }
  }
}

// ---------------- fused attention v3: energy+softmax+P-store+PV ------------
// Swapped QK^T (A=K, B=Q): lane holds P[q=q0+lr][k = w*256 + kt*16 + lh*4 + r].
// Scaled P (f32) staged in 64KB LDS tile, XOR-swizzled at 16B granule:
//   logical granule g of row r lives at physical granule g ^ (r&7).
// P global stores: each wave stores 4 FULL rows, 1KB contiguous per
// instruction (fixes the 4KB-lane-stride scatter that throttled R5-R10).
// PV reads A-frags from the same LDS (f32 -> bf16 in-register): no P re-read.
__global__ __launch_bounds__(256, 2) void attn3_kernel(const u16* __restrict__ Qh,
                                                       const u16* __restrict__ Kh,
                                                       const u16* __restrict__ Qsh,
                                                       const u16* __restrict__ Ksh,
                                                       const u16* __restrict__ Vth,
                                                       const uint32_t* __restrict__ mbits,
                                                       float* __restrict__ Pout,
                                                       u16* __restrict__ ctx) {
  __shared__ __align__(16) float Pf[16 * 1024]; // 64 KB
  __shared__ float redM[4][16];
  __shared__ float redS[4][16];
  const int t = threadIdx.x, w = t >> 6, l = t & 63;
  const int lr = l & 15, lh = l >> 4;
  // XCD-aware remap: 64 q-tiles of one head stay on one XCD
  int lid = blockIdx.y * 64 + blockIdx.x;
  int xcd = lid & 7, j = lid >> 3;
  int bh = xcd * 8 + (j >> 6);
  int q0 = (j & 63) << 4;
  const int b = bh >> 4, h = bh & 15;
  const size_t hoff = (size_t)bh * Sc * HDc;

  // ---- Q fragments ----
  const u16* Qp = Qh + hoff + (size_t)(q0 + lr) * HDc + lh * 8;
  const u16* Qsp = Qsh + hoff + (size_t)(q0 + lr) * HDc + lh * 8;
  bf16x8 qf0 = *(const bf16x8*)Qp, qf1 = *(const bf16x8*)(Qp + 32);
  bf16x8 sf0 = *(const bf16x8*)Qsp, sf1 = *(const bf16x8*)(Qsp + 32);

  // ---- mask words for this lane's q-row, k-window [w*256,(w+1)*256) ----
  uint32_t mwreg[8];
  {
    const uint32_t* mrow_l = mbits + ((size_t)b * Sc + q0 + lr) * 32 + w * 8;
    *(uint4*)&mwreg[0] = *(const uint4*)mrow_l;
    *(uint4*)&mwreg[4] = *(const uint4*)(mrow_l + 4);
  }

  // ---- energy: wave w covers k in [w*256, w*256+256), depth-3 K prefetch ----
  const u16* Kbase = Kh + hoff + (size_t)((w << 8) + lr) * HDc + lh * 8;
  const u16* Ksbase = Ksh + hoff + (size_t)((w << 8) + lr) * HDc + lh * 8;

  bf16x8 ka[3], kb[3], sa[3], sb[3];
#define LOADK(slot, it) do { \
    const u16* Kp_ = Kbase + (it) * (16 * HDc); \
    const u16* Sp_ = Ksbase + (it) * (16 * HDc); \
    ka[slot] = *(const bf16x8*)Kp_;  kb[slot] = *(const bf16x8*)(Kp_ + 32); \
    sa[slot] = *(const bf16x8*)Sp_;  sb[slot] = *(const bf16x8*)(Sp_ + 32); } while (0)

  LOADK(0, 0); LOADK(1, 1); LOADK(2, 2);

  f32x4 p[16];
#pragma unroll
  for (int kt = 0; kt < 16; ++kt) {
    const int s = kt % 3;
    f32x4 e = {}, es = {};
    e = mfma16(ka[s], qf0, e);
    e = mfma16(kb[s], qf1, e);
    es = mfma16(sa[s], sf0, es);
    es = mfma16(sb[s], sf1, es);
    if (kt + 3 < 16) LOADK(s, kt + 3);
    uint32_t md = mwreg[kt >> 1];
    int sh = ((kt & 1) << 4) + (lh << 2);
    f32x4 r;
    r[0] = ((md >> (sh + 0)) & 1u ? es[0] : e[0]) * 0.125f;
    r[1] = ((md >> (sh + 1)) & 1u ? es[1] : e[1]) * 0.125f;
    r[2] = ((md >> (sh + 2)) & 1u ? es[2] : e[2]) * 0.125f;
    r[3] = ((md >> (sh + 3)) & 1u ? es[3] : e[3]) * 0.125f;
    p[kt] = r;
  }
#undef LOADK

  // ---- wave-local softmax stats ----
  float mw = -1e30f;
#pragma unroll
  for (int kt = 0; kt < 16; ++kt)
    mw = fmaxf(mw, fmaxf(fmaxf(p[kt][0], p[kt][1]), fmaxf(p[kt][2], p[kt][3])));
  mw = fmaxf(mw, __shfl_xor(mw, 16));
  mw = fmaxf(mw, __shfl_xor(mw, 32));
  float sw = 0.f;
#pragma unroll
  for (int kt = 0; kt < 16; ++kt) {
#pragma unroll
    for (int i = 0; i < 4; ++i) { float tt = __expf(p[kt][i] - mw); p[kt][i] = tt; sw += tt; }
  }
  sw += __shfl_xor(sw, 16);
  sw += __shfl_xor(sw, 32);
  if (lh == 0) { redM[w][lr] = mw; redS[w][lr] = sw; }
  __syncthreads();

  // ---- cross-wave combine (per q-row lr) ----
  float m0_ = redM[0][lr], m1_ = redM[1][lr], m2_ = redM[2][lr], m3_ = redM[3][lr];
  float gm = fmaxf(fmaxf(m0_, m1_), fmaxf(m2_, m3_));
  float gsum = redS[0][lr] * __expf(m0_ - gm) + redS[1][lr] * __expf(m1_ - gm) +
               redS[2][lr] * __expf(m2_ - gm) + redS[3][lr] * __expf(m3_ - gm);
  const float scale = __expf(mw - gm) / gsum;

  // ---- scaled P -> LDS (f32, swizzled) ----
  const int slr = lr & 7;
#pragma unroll
  for (int kt = 0; kt < 16; ++kt) {
    f32x4 pv = p[kt] * scale;
    int g = (w << 6) + (kt << 2) + lh;   // logical granule (16B) within row
    *(f32x4*)&Pf[(lr << 10) + ((g ^ slr) << 2)] = pv;
  }

  // ---- V prefetch (depth-2) issued before the barrier ----
  const u16* Vbp = Vth + ((size_t)bh * HDc + (w << 4) + lr) * Sc + lh * 8;
  bf16x8 va[2], vb[2];
#define LOADV(slot, it) do { \
    va[slot] = *(const bf16x8*)(Vbp + (it) * 64); \
    vb[slot] = *(const bf16x8*)(Vbp + (it) * 64 + 32); } while (0)
  LOADV(0, 0); LOADV(1, 1);

  __syncthreads();

  // ---- P store phase: wave w stores rows w*4..w*4+3, fully coalesced ----
  float* Pb = Pout + ((size_t)bh * Sc + q0) * Sc;
#pragma unroll
  for (int r4 = 0; r4 < 4; ++r4) {
    int row = (w << 2) + r4, s = row & 7;
#pragma unroll
    for (int c = 0; c < 4; ++c) {
      int g = (c << 6) + l;
      f32x4 v = *(const f32x4*)&Pf[(row << 10) + ((g ^ s) << 2)];
      *(f32x4*)(Pb + (size_t)row * Sc + (c << 8) + (l << 2)) = v;
    }
  }

  // ---- PV: wave w handles d-cols [w*16, w*16+16); A-frags from LDS f32 ----
  f32x4 acc0 = {}, acc1 = {};
#pragma unroll
  for (int it = 0; it < 16; ++it) {
    const int s = it & 1;
    int g0 = (it << 4) + (lh << 1);     // k = it*64 + lh*8 -> granule
    f32x4 x0 = *(const f32x4*)&Pf[(lr << 10) + ((g0 ^ slr) << 2)];
    f32x4 x1 = *(const f32x4*)&Pf[(lr << 10) + (((g0 + 1) ^ slr) << 2)];
    f32x4 x2 = *(const f32x4*)&Pf[(lr << 10) + (((g0 + 8) ^ slr) << 2)];
    f32x4 x3 = *(const f32x4*)&Pf[(lr << 10) + (((g0 + 9) ^ slr) << 2)];
    union { bf16x8 v; u16 sx[8]; } a0, a1;
#pragma unroll
    for (int i = 0; i < 4; ++i) {
      a0.sx[i] = f2bf(x0[i]); a0.sx[4 + i] = f2bf(x1[i]);
      a1.sx[i] = f2bf(x2[i]); a1.sx[4 + i] = f2bf(x3[i]);
    }
    acc0 = mfma16(a0.v, va[s], acc0);
    acc1 = mfma16(a1.v, vb[s], acc1);
    if (it + 2 < 16) LOADV(s, it + 2);
  }
#undef LOADV
  f32x4 acc = acc0 + acc1;
#pragma unroll
  for (int r = 0; r < 4; ++r) {
    int row = q0 + (lh << 2) + r;
    ctx[((size_t)b * Sc + row) * Hc + (h << 6) + (w << 4) + lr] = f2bf(acc[r]);
  }
}

extern "C" void kernel_launch(void* const* d_in, const int* in_sizes, int n_in,
                              void* d_out, int out_size, void* d_ws, size_t ws_size,
                              hipStream_t stream) {
  const float* fin[5] = { (const float*)d_in[0], (const float*)d_in[1], (const float*)d_in[2],
                          (const float*)d_in[3], (const float*)d_in[4] };
  const int* mask = (const int*)d_in[5];
  const float* W[6] = { (const float*)d_in[6], (const float*)d_in[8], (const float*)d_in[10],
                        (const float*)d_in[12], (const float*)d_in[14], (const float*)d_in[16] };
  const float* bias[6] = { (const float*)d_in[7], (const float*)d_in[9], (const float*)d_in[11],
                           (const float*)d_in[13], (const float*)d_in[15], (const float*)d_in[17] };

  float* out_x = (float*)d_out;
  float* out_attn = out_x + (size_t)Bc * Sc * Hc;

  const size_t NE = (size_t)Bc * Sc * Hc; // 4M elems
  const size_t NW = (size_t)Hc * Hc;      // 1M elems
  u16* p = (u16*)d_ws;
  u16* xin[5]; for (int i = 0; i < 5; ++i) { xin[i] = p; p += NE; }
  u16* wbf[6]; for (int i = 0; i < 6; ++i) { wbf[i] = p; p += NW; }
  u16* Qh  = p; p += NE;
  u16* Kh  = p; p += NE;
  u16* Qsh = p; p += NE;
  u16* Ksh = p; p += NE;
  u16* Vth = p; p += NE;
  u16* ctx = p; p += NE;
  uint32_t* mbits = (uint32_t*)xin[0]; // reused after proj5

  {
    CV a{};
    for (int i = 0; i < 5; ++i) { a.in[i] = fin[i]; a.out[i] = xin[i]; }
    cvtN_kernel<<<dim3((int)(NE / 8 / 256), 1, 5), 256, 0, stream>>>(a, (int)(NE / 8));
  }
  {
    CV a{};
    for (int i = 0; i < 6; ++i) { a.in[i] = W[i]; a.out[i] = wbf[i]; }
    cvtN_kernel<<<dim3((int)(NW / 8 / 256), 1, 6), 256, 0, stream>>>(a, (int)(NW / 8));
  }

  P5 args;
  u16* projout[5] = { Qh, Kh, Qsh, Ksh, Vth };
  for (int i = 0; i < 5; ++i) { args.A[i] = xin[i]; args.W[i] = wbf[i]; args.b[i] = bias[i]; args.o[i] = projout[i]; }
  proj5_kernel<<<dim3(Hc / 128, Mrows / 128, 5), 256, 0, stream>>>(args);

  maskpack_kernel<<<(int)((size_t)Bc * Sc * Sc / 32 / 256), 256, 0, stream>>>(mask, mbits);

  attn3_kernel<<<dim3(Sc / 16, Bc * NHc), 256, 0, stream>>>(Qh, Kh, Qsh, Ksh, Vth, mbits, out_attn, ctx);

  gemmo_kernel<<<dim3(Hc / 128, Mrows / 128), 256, 0, stream>>>(ctx, wbf[5], bias[5], out_x);
}

// Round 12
// 347.134 us; speedup vs baseline: 1.2679x; 1.0248x over previous
//
#include <hip/hip_runtime.h>
#include <hip/hip_bf16.h>
#include <stdint.h>

typedef uint16_t u16;
typedef __attribute__((ext_vector_type(8))) short bf16x8;
typedef __attribute__((ext_vector_type(4))) float f32x4;

#define DEVI static __device__ __forceinline__
#define GLOAD_LDS(gptr, lptr) \
  __builtin_amdgcn_global_load_lds((const __attribute__((address_space(1))) void*)(gptr), \
                                   (__attribute__((address_space(3))) void*)(lptr), 16, 0, 0)

constexpr int Bc = 4, Sc = 1024, Hc = 1024, NHc = 16, HDc = 64;
constexpr int Mrows = Bc * Sc; // 4096

DEVI u16 f2bf(float f) {
  uint32_t u = __builtin_bit_cast(uint32_t, f);
  u += 0x7FFFu + ((u >> 16) & 1u);
  return (u16)(u >> 16);
}
DEVI float bf2f(u16 x) { return __builtin_bit_cast(float, (uint32_t)x << 16); }

DEVI f32x4 mfma16(bf16x8 a, bf16x8 b, f32x4 c) {
  return __builtin_amdgcn_mfma_f32_16x16x32_bf16(a, b, c, 0, 0, 0);
}

// ---------------- batched f32 -> bf16 conversion ----------------
struct CV { const float* in[6]; u16* out[6]; };

__global__ __launch_bounds__(256) void cvtN_kernel(CV a, int n8) {
  int z = blockIdx.z;
  int i = blockIdx.x * 256 + threadIdx.x;
  if (i >= n8) return;
  const f32x4* p = (const f32x4*)(a.in[z] + (size_t)i * 8);
  f32x4 x = p[0], y = p[1];
  union { bf16x8 v; u16 s[8]; } r;
#pragma unroll
  for (int j = 0; j < 4; ++j) { r.s[j] = f2bf(x[j]); r.s[4 + j] = f2bf(y[j]); }
  *(bf16x8*)(a.out[z] + (size_t)i * 8) = r.v;
}

// ---------------- mask int32 -> bitmask ----------------
__global__ __launch_bounds__(256) void maskpack_kernel(const int* __restrict__ mask,
                                                       uint32_t* __restrict__ out) {
  int i = blockIdx.x * 256 + threadIdx.x;
  const int4* p = (const int4*)(mask + (size_t)i * 32);
  uint32_t r = 0;
#pragma unroll
  for (int j = 0; j < 8; ++j) {
    int4 v = p[j];
    uint32_t nib = (v.x ? 1u : 0u) | (v.y ? 2u : 0u) | (v.z ? 4u : 0u) | (v.w ? 8u : 0u);
    r |= nib << (j * 4);
  }
  out[i] = r;
}

// ---------------- fused 5-way projection GEMM ----------------
struct P5 { const u16* A[5]; const u16* W[5]; const float* b[5]; u16* o[5]; };

__global__ __launch_bounds__(256) void proj5_kernel(P5 args) {
  constexpr int K = 1024, BK = 32;
  __shared__ u16 As[128 * BK];
  __shared__ u16 Bs[128 * BK];
  const int z = blockIdx.z;
  const u16* __restrict__ A = args.A[z];
  const u16* __restrict__ Bw = args.W[z];
  const float* __restrict__ bias = args.b[z];
  u16* __restrict__ Cout = args.o[z];
  const int t = threadIdx.x;
  const int w = t >> 6, l = t & 63;
  const int lr = l & 15, lh = l >> 4;
  const int m0 = blockIdx.y * 128, n0 = blockIdx.x * 128;
  const int wr = w >> 1, wc = w & 1;
  f32x4 acc[4][4] = {};

  const int row_s = t >> 2, k8 = (t & 3) << 3;
  const u16* ga = A + (size_t)(m0 + row_s) * K + k8;
  const u16* gb = Bw + (size_t)(n0 + row_s) * K + k8;

  for (int kt = 0; kt < K; kt += BK) {
    GLOAD_LDS(ga + kt, As + t * 8);
    GLOAD_LDS(ga + (size_t)64 * K + kt, As + 2048 + t * 8);
    GLOAD_LDS(gb + kt, Bs + t * 8);
    GLOAD_LDS(gb + (size_t)64 * K + kt, Bs + 2048 + t * 8);
    __syncthreads();
    bf16x8 af[4], bfr[4];
#pragma unroll
    for (int mi = 0; mi < 4; ++mi)
      af[mi] = *(const bf16x8*)(As + (wr * 64 + mi * 16 + lr) * BK + lh * 8);
#pragma unroll
    for (int ni = 0; ni < 4; ++ni)
      bfr[ni] = *(const bf16x8*)(Bs + (wc * 64 + ni * 16 + lr) * BK + lh * 8);
#pragma unroll
    for (int mi = 0; mi < 4; ++mi)
#pragma unroll
      for (int ni = 0; ni < 4; ++ni)
        acc[mi][ni] = mfma16(af[mi], bfr[ni], acc[mi][ni]);
    __syncthreads();
  }

#pragma unroll
  for (int mi = 0; mi < 4; ++mi) {
#pragma unroll
    for (int ni = 0; ni < 4; ++ni) {
      int col = n0 + wc * 64 + ni * 16 + lr;
      float bc = bias[col];
      int hcol = col >> 6, dcol = col & 63;
      int rbase = m0 + wr * 64 + mi * 16 + lh * 4;
      int bb = rbase >> 10, sb = rbase & 1023;
      if (z == 4) {
        ushort4 pk;
        pk.x = f2bf(acc[mi][ni][0] + bc);
        pk.y = f2bf(acc[mi][ni][1] + bc);
        pk.z = f2bf(acc[mi][ni][2] + bc);
        pk.w = f2bf(acc[mi][ni][3] + bc);
        *(ushort4*)&Cout[((size_t)(bb * NHc + hcol) * HDc + dcol) * Sc + sb] = pk;
      } else {
#pragma unroll
        for (int r = 0; r < 4; ++r)
          Cout[((size_t)(bb * NHc + hcol) * Sc + (sb + r)) * HDc + dcol] =
              f2bf(acc[mi][ni][r] + bc);
      }
    }
  }
}

// ---------------- output projection GEMM (f32 out, [M,N]) ----------------
__global__ __launch_bounds__(256) void gemmo_kernel(const u16* __restrict__ A,
                                                    const u16* __restrict__ Bw,
                                                    const float* __restrict__ bias,
                                                    float* __restrict__ Cout) {
  constexpr int K = 1024, N = 1024, BK = 32;
  __shared__ u16 As[128 * BK];
  __shared__ u16 Bs[128 * BK];
  const int t = threadIdx.x;
  const int w = t >> 6, l = t & 63;
  const int lr = l & 15, lh = l >> 4;
  const int m0 = blockIdx.y * 128, n0 = blockIdx.x * 128;
  const int wr = w >> 1, wc = w & 1;
  f32x4 acc[4][4] = {};

  const int row_s = t >> 2, k8 = (t & 3) << 3;
  const u16* ga = A + (size_t)(m0 + row_s) * K + k8;
  const u16* gb = Bw + (size_t)(n0 + row_s) * K + k8;

  for (int kt = 0; kt < K; kt += BK) {
    GLOAD_LDS(ga + kt, As + t * 8);
    GLOAD_LDS(ga + (size_t)64 * K + kt, As + 2048 + t * 8);
    GLOAD_LDS(gb + kt, Bs + t * 8);
    GLOAD_LDS(gb + (size_t)64 * K + kt, Bs + 2048 + t * 8);
    __syncthreads();
    bf16x8 af[4], bfr[4];
#pragma unroll
    for (int mi = 0; mi < 4; ++mi)
      af[mi] = *(const bf16x8*)(As + (wr * 64 + mi * 16 + lr) * BK + lh * 8);
#pragma unroll
    for (int ni = 0; ni < 4; ++ni)
      bfr[ni] = *(const bf16x8*)(Bs + (wc * 64 + ni * 16 + lr) * BK + lh * 8);
#pragma unroll
    for (int mi = 0; mi < 4; ++mi)
#pragma unroll
      for (int ni = 0; ni < 4; ++ni)
        acc[mi][ni] = mfma16(af[mi], bfr[ni], acc[mi][ni]);
    __syncthreads();
  }

#pragma unroll
  for (int mi = 0; mi < 4; ++mi) {
#pragma unroll
    for (int ni = 0; ni < 4; ++ni) {
      int col = n0 + wc * 64 + ni * 16 + lr;
      float bc = bias[col];
#pragma unroll
      for (int r = 0; r < 4; ++r) {
        int rowg = m0 + wr * 64 + mi * 16 + lh * 4 + r;
        Cout[(size_t)rowg * N + col] = acc[mi][ni][r] + bc;
      }
    }
  }
}

// ---------------- fused attention v4: energy+softmax+P-store+PV ------------
// Swapped QK^T (A=K, B=Q): lane holds P[q=q0+lr][k = w*256 + kt*16 + lh*4 + r].
// Scaled P staged in 32KB BF16 LDS tile (swizzled 16B granule):
//   u16 index(row,k) = row*1024 + (((k>>3) ^ (row&7)) << 3) | (k&7)
// -> 4 blocks/CU (vs 2 with f32 tile): resident blocks de-stagger, stores of
//    one block overlap compute of others.
// P global stores: per wave 4 FULL rows, 1KB-contiguous NONTEMPORAL f32x4
// (bf16 -> f32 expand in-register) - no L2 churn against K/Ks/V.
// PV reads bf16 A-frags straight from LDS (R6-proven layout).
__global__ __launch_bounds__(256, 4) void attn4_kernel(const u16* __restrict__ Qh,
                                                       const u16* __restrict__ Kh,
                                                       const u16* __restrict__ Qsh,
                                                       const u16* __restrict__ Ksh,
                                                       const u16* __restrict__ Vth,
                                                       const uint32_t* __restrict__ mbits,
                                                       float* __restrict__ Pout,
                                                       u16* __restrict__ ctx) {
  __shared__ __align__(16) u16 E[16 * 1024]; // 32 KB bf16
  __shared__ float redM[4][16];
  __shared__ float redS[4][16];
  const int t = threadIdx.x, w = t >> 6, l = t & 63;
  const int lr = l & 15, lh = l >> 4;
  // XCD-aware remap: 64 q-tiles of one head stay on one XCD
  int lid = blockIdx.y * 64 + blockIdx.x;
  int xcd = lid & 7, j = lid >> 3;
  int bh = xcd * 8 + (j >> 6);
  int q0 = (j & 63) << 4;
  const int b = bh >> 4, h = bh & 15;
  const size_t hoff = (size_t)bh * Sc * HDc;

  // ---- Q fragments ----
  const u16* Qp = Qh + hoff + (size_t)(q0 + lr) * HDc + lh * 8;
  const u16* Qsp = Qsh + hoff + (size_t)(q0 + lr) * HDc + lh * 8;
  bf16x8 qf0 = *(const bf16x8*)Qp, qf1 = *(const bf16x8*)(Qp + 32);
  bf16x8 sf0 = *(const bf16x8*)Qsp, sf1 = *(const bf16x8*)(Qsp + 32);

  // ---- mask words for this lane's q-row, k-window [w*256,(w+1)*256) ----
  uint32_t mwreg[8];
  {
    const uint32_t* mrow_l = mbits + ((size_t)b * Sc + q0 + lr) * 32 + w * 8;
    *(uint4*)&mwreg[0] = *(const uint4*)mrow_l;
    *(uint4*)&mwreg[4] = *(const uint4*)(mrow_l + 4);
  }

  // ---- energy: wave w covers k in [w*256, w*256+256), depth-3 K prefetch ----
  const u16* Kbase = Kh + hoff + (size_t)((w << 8) + lr) * HDc + lh * 8;
  const u16* Ksbase = Ksh + hoff + (size_t)((w << 8) + lr) * HDc + lh * 8;

  bf16x8 ka[3], kb[3], sa[3], sb[3];
#define LOADK(slot, it) do { \
    const u16* Kp_ = Kbase + (it) * (16 * HDc); \
    const u16* Sp_ = Ksbase + (it) * (16 * HDc); \
    ka[slot] = *(const bf16x8*)Kp_;  kb[slot] = *(const bf16x8*)(Kp_ + 32); \
    sa[slot] = *(const bf16x8*)Sp_;  sb[slot] = *(const bf16x8*)(Sp_ + 32); } while (0)

  LOADK(0, 0); LOADK(1, 1); LOADK(2, 2);

  f32x4 p[16];
#pragma unroll
  for (int kt = 0; kt < 16; ++kt) {
    const int s = kt % 3;
    f32x4 e = {}, es = {};
    e = mfma16(ka[s], qf0, e);
    e = mfma16(kb[s], qf1, e);
    es = mfma16(sa[s], sf0, es);
    es = mfma16(sb[s], sf1, es);
    if (kt + 3 < 16) LOADK(s, kt + 3);
    uint32_t md = mwreg[kt >> 1];
    int sh = ((kt & 1) << 4) + (lh << 2);
    f32x4 r;
    r[0] = ((md >> (sh + 0)) & 1u ? es[0] : e[0]) * 0.125f;
    r[1] = ((md >> (sh + 1)) & 1u ? es[1] : e[1]) * 0.125f;
    r[2] = ((md >> (sh + 2)) & 1u ? es[2] : e[2]) * 0.125f;
    r[3] = ((md >> (sh + 3)) & 1u ? es[3] : e[3]) * 0.125f;
    p[kt] = r;
  }
#undef LOADK

  // ---- wave-local softmax stats ----
  float mw = -1e30f;
#pragma unroll
  for (int kt = 0; kt < 16; ++kt)
    mw = fmaxf(mw, fmaxf(fmaxf(p[kt][0], p[kt][1]), fmaxf(p[kt][2], p[kt][3])));
  mw = fmaxf(mw, __shfl_xor(mw, 16));
  mw = fmaxf(mw, __shfl_xor(mw, 32));
  float sw = 0.f;
#pragma unroll
  for (int kt = 0; kt < 16; ++kt) {
#pragma unroll
    for (int i = 0; i < 4; ++i) { float tt = __expf(p[kt][i] - mw); p[kt][i] = tt; sw += tt; }
  }
  sw += __shfl_xor(sw, 16);
  sw += __shfl_xor(sw, 32);
  if (lh == 0) { redM[w][lr] = mw; redS[w][lr] = sw; }
  __syncthreads();

  // ---- cross-wave combine (per q-row lr) ----
  float m0_ = redM[0][lr], m1_ = redM[1][lr], m2_ = redM[2][lr], m3_ = redM[3][lr];
  float gm = fmaxf(fmaxf(m0_, m1_), fmaxf(m2_, m3_));
  float gsum = redS[0][lr] * __expf(m0_ - gm) + redS[1][lr] * __expf(m1_ - gm) +
               redS[2][lr] * __expf(m2_ - gm) + redS[3][lr] * __expf(m3_ - gm);
  const float scale = __expf(mw - gm) / gsum;

  // ---- scaled P -> LDS bf16 (swizzled) ----
#pragma unroll
  for (int kt = 0; kt < 16; ++kt) {
    f32x4 pv = p[kt] * scale;
    ushort4 wb;
    wb.x = f2bf(pv[0]); wb.y = f2bf(pv[1]); wb.z = f2bf(pv[2]); wb.w = f2bf(pv[3]);
    int kb16 = (w << 8) + (kt << 4) + (lh << 2);
    *(ushort4*)&E[(lr << 10) + ((((kb16 >> 3) ^ (lr & 7)) << 3) | (kb16 & 7))] = wb;
  }

  // ---- V prefetch (depth-2) issued before the barrier ----
  const u16* Vbp = Vth + ((size_t)bh * HDc + (w << 4) + lr) * Sc + lh * 8;
  bf16x8 va[2], vb[2];
#define LOADV(slot, it) do { \
    va[slot] = *(const bf16x8*)(Vbp + (it) * 64); \
    vb[slot] = *(const bf16x8*)(Vbp + (it) * 64 + 32); } while (0)
  LOADV(0, 0); LOADV(1, 1);

  __syncthreads();

  // ---- P store phase: wave w stores rows w*4..w*4+3 ----
  // lane l handles f32 cols c*256 + l*4 (+0..3): 1KB-contiguous NT stores.
  float* Pb = Pout + ((size_t)bh * Sc + q0) * Sc;
#pragma unroll
  for (int r4 = 0; r4 < 4; ++r4) {
    int row = (w << 2) + r4, s = row & 7;
#pragma unroll
    for (int c = 0; c < 4; ++c) {
      int k = (c << 8) + (l << 2);
      ushort4 raw = *(const ushort4*)&E[(row << 10) + ((((k >> 3) ^ s) << 3) | (k & 7))];
      f32x4 v = { bf2f(raw.x), bf2f(raw.y), bf2f(raw.z), bf2f(raw.w) };
      __builtin_nontemporal_store(v, (f32x4*)(Pb + (size_t)row * Sc + k));
    }
  }

  // ---- PV: wave w handles d-cols [w*16, w*16+16); bf16 A-frags from LDS ----
  const int swp = lr & 7;
  f32x4 acc0 = {}, acc1 = {};
#pragma unroll
  for (int it = 0; it < 16; ++it) {
    const int s = it & 1;
    int ka16 = (it << 6) + (lh << 3);
    bf16x8 a0 = *(const bf16x8*)&E[(lr << 10) + (((ka16 >> 3) ^ swp) << 3)];
    bf16x8 a1 = *(const bf16x8*)&E[(lr << 10) + ((((ka16 + 32) >> 3) ^ swp) << 3)];
    acc0 = mfma16(a0, va[s], acc0);
    acc1 = mfma16(a1, vb[s], acc1);
    if (it + 2 < 16) LOADV(s, it + 2);
  }
#undef LOADV
  f32x4 acc = acc0 + acc1;
#pragma unroll
  for (int r = 0; r < 4; ++r) {
    int row = q0 + (lh << 2) + r;
    ctx[((size_t)b * Sc + row) * Hc + (h << 6) + (w << 4) + lr] = f2bf(acc[r]);
  }
}

extern "C" void kernel_launch(void* const* d_in, const int* in_sizes, int n_in,
                              void* d_out, int out_size, void* d_ws, size_t ws_size,
                              hipStream_t stream) {
  const float* fin[5] = { (const float*)d_in[0], (const float*)d_in[1], (const float*)d_in[2],
                          (const float*)d_in[3], (const float*)d_in[4] };
  const int* mask = (const int*)d_in[5];
  const float* W[6] = { (const float*)d_in[6], (const float*)d_in[8], (const float*)d_in[10],
                        (const float*)d_in[12], (const float*)d_in[14], (const float*)d_in[16] };
  const float* bias[6] = { (const float*)d_in[7], (const float*)d_in[9], (const float*)d_in[11],
                           (const float*)d_in[13], (const float*)d_in[15], (const float*)d_in[17] };

  float* out_x = (float*)d_out;
  float* out_attn = out_x + (size_t)Bc * Sc * Hc;

  const size_t NE = (size_t)Bc * Sc * Hc; // 4M elems
  const size_t NW = (size_t)Hc * Hc;      // 1M elems
  u16* p = (u16*)d_ws;
  u16* xin[5]; for (int i = 0; i < 5; ++i) { xin[i] = p; p += NE; }
  u16* wbf[6]; for (int i = 0; i < 6; ++i) { wbf[i] = p; p += NW; }
  u16* Qh  = p; p += NE;
  u16* Kh  = p; p += NE;
  u16* Qsh = p; p += NE;
  u16* Ksh = p; p += NE;
  u16* Vth = p; p += NE;
  u16* ctx = p; p += NE;
  uint32_t* mbits = (uint32_t*)xin[0]; // reused after proj5

  {
    CV a{};
    for (int i = 0; i < 5; ++i) { a.in[i] = fin[i]; a.out[i] = xin[i]; }
    cvtN_kernel<<<dim3((int)(NE / 8 / 256), 1, 5), 256, 0, stream>>>(a, (int)(NE / 8));
  }
  {
    CV a{};
    for (int i = 0; i < 6; ++i) { a.in[i] = W[i]; a.out[i] = wbf[i]; }
    cvtN_kernel<<<dim3((int)(NW / 8 / 256), 1, 6), 256, 0, stream>>>(a, (int)(NW / 8));
  }

  P5 args;
  u16* projout[5] = { Qh, Kh, Qsh, Ksh, Vth };
  for (int i = 0; i < 5; ++i) { args.A[i] = xin[i]; args.W[i] = wbf[i]; args.b[i] = bias[i]; args.o[i] = projout[i]; }
  proj5_kernel<<<dim3(Hc / 128, Mrows / 128, 5), 256, 0, stream>>>(args);

  maskpack_kernel<<<(int)((size_t)Bc * Sc * Sc / 32 / 256), 256, 0, stream>>>(mask, mbits);

  attn4_kernel<<<dim3(Sc / 16, Bc * NHc), 256, 0, stream>>>(Qh, Kh, Qsh, Ksh, Vth, mbits, out_attn, ctx);

  gemmo_kernel<<<dim3(Hc / 128, Mrows / 128), 256, 0, stream>>>(ctx, wbf[5], bias[5], out_x);
}

// Round 13
// 290.571 us; speedup vs baseline: 1.5147x; 1.1947x over previous
//
#include <hip/hip_runtime.h>
#include <hip/hip_bf16.h>
#include <stdint.h>

typedef uint16_t u16;
typedef __attribute__((ext_vector_type(8))) short bf16x8;
typedef __attribute__((ext_vector_type(4))) float f32x4;

#define DEVI static __device__ __forceinline__
#define GLOAD_LDS(gptr, lptr) \
  __builtin_amdgcn_global_load_lds((const __attribute__((address_space(1))) void*)(gptr), \
                                   (__attribute__((address_space(3))) void*)(lptr), 16, 0, 0)

constexpr int Bc = 4, Sc = 1024, Hc = 1024, NHc = 16, HDc = 64;
constexpr int Mrows = Bc * Sc; // 4096

DEVI u16 f2bf(float f) {
  uint32_t u = __builtin_bit_cast(uint32_t, f);
  u += 0x7FFFu + ((u >> 16) & 1u);
  return (u16)(u >> 16);
}
DEVI float bf2f(u16 x) { return __builtin_bit_cast(float, (uint32_t)x << 16); }

DEVI f32x4 mfma16(bf16x8 a, bf16x8 b, f32x4 c) {
  return __builtin_amdgcn_mfma_f32_16x16x32_bf16(a, b, c, 0, 0, 0);
}

// ---------------- batched f32 -> bf16 conversion ----------------
struct CV { const float* in[6]; u16* out[6]; };

__global__ __launch_bounds__(256) void cvtN_kernel(CV a, int n8) {
  int z = blockIdx.z;
  int i = blockIdx.x * 256 + threadIdx.x;
  if (i >= n8) return;
  const f32x4* p = (const f32x4*)(a.in[z] + (size_t)i * 8);
  f32x4 x = p[0], y = p[1];
  union { bf16x8 v; u16 s[8]; } r;
#pragma unroll
  for (int j = 0; j < 4; ++j) { r.s[j] = f2bf(x[j]); r.s[4 + j] = f2bf(y[j]); }
  *(bf16x8*)(a.out[z] + (size_t)i * 8) = r.v;
}

// ---------------- mask int32 -> bitmask ----------------
__global__ __launch_bounds__(256) void maskpack_kernel(const int* __restrict__ mask,
                                                       uint32_t* __restrict__ out) {
  int i = blockIdx.x * 256 + threadIdx.x;
  const int4* p = (const int4*)(mask + (size_t)i * 32);
  uint32_t r = 0;
#pragma unroll
  for (int j = 0; j < 8; ++j) {
    int4 v = p[j];
    uint32_t nib = (v.x ? 1u : 0u) | (v.y ? 2u : 0u) | (v.z ? 4u : 0u) | (v.w ? 8u : 0u);
    r |= nib << (j * 4);
  }
  out[i] = r;
}

// ---------------- fused 5-way projection GEMM ----------------
struct P5 { const u16* A[5]; const u16* W[5]; const float* b[5]; u16* o[5]; };

__global__ __launch_bounds__(256) void proj5_kernel(P5 args) {
  constexpr int K = 1024, BK = 32;
  __shared__ u16 As[128 * BK];
  __shared__ u16 Bs[128 * BK];
  const int z = blockIdx.z;
  const u16* __restrict__ A = args.A[z];
  const u16* __restrict__ Bw = args.W[z];
  const float* __restrict__ bias = args.b[z];
  u16* __restrict__ Cout = args.o[z];
  const int t = threadIdx.x;
  const int w = t >> 6, l = t & 63;
  const int lr = l & 15, lh = l >> 4;
  const int m0 = blockIdx.y * 128, n0 = blockIdx.x * 128;
  const int wr = w >> 1, wc = w & 1;
  f32x4 acc[4][4] = {};

  const int row_s = t >> 2, k8 = (t & 3) << 3;
  const u16* ga = A + (size_t)(m0 + row_s) * K + k8;
  const u16* gb = Bw + (size_t)(n0 + row_s) * K + k8;

  for (int kt = 0; kt < K; kt += BK) {
    GLOAD_LDS(ga + kt, As + t * 8);
    GLOAD_LDS(ga + (size_t)64 * K + kt, As + 2048 + t * 8);
    GLOAD_LDS(gb + kt, Bs + t * 8);
    GLOAD_LDS(gb + (size_t)64 * K + kt, Bs + 2048 + t * 8);
    __syncthreads();
    bf16x8 af[4], bfr[4];
#pragma unroll
    for (int mi = 0; mi < 4; ++mi)
      af[mi] = *(const bf16x8*)(As + (wr * 64 + mi * 16 + lr) * BK + lh * 8);
#pragma unroll
    for (int ni = 0; ni < 4; ++ni)
      bfr[ni] = *(const bf16x8*)(Bs + (wc * 64 + ni * 16 + lr) * BK + lh * 8);
#pragma unroll
    for (int mi = 0; mi < 4; ++mi)
#pragma unroll
      for (int ni = 0; ni < 4; ++ni)
        acc[mi][ni] = mfma16(af[mi], bfr[ni], acc[mi][ni]);
    __syncthreads();
  }

#pragma unroll
  for (int mi = 0; mi < 4; ++mi) {
#pragma unroll
    for (int ni = 0; ni < 4; ++ni) {
      int col = n0 + wc * 64 + ni * 16 + lr;
      float bc = bias[col];
      int hcol = col >> 6, dcol = col & 63;
      int rbase = m0 + wr * 64 + mi * 16 + lh * 4;
      int bb = rbase >> 10, sb = rbase & 1023;
      if (z == 4) {
        ushort4 pk;
        pk.x = f2bf(acc[mi][ni][0] + bc);
        pk.y = f2bf(acc[mi][ni][1] + bc);
        pk.z = f2bf(acc[mi][ni][2] + bc);
        pk.w = f2bf(acc[mi][ni][3] + bc);
        *(ushort4*)&Cout[((size_t)(bb * NHc + hcol) * HDc + dcol) * Sc + sb] = pk;
      } else {
#pragma unroll
        for (int r = 0; r < 4; ++r)
          Cout[((size_t)(bb * NHc + hcol) * Sc + (sb + r)) * HDc + dcol] =
              f2bf(acc[mi][ni][r] + bc);
      }
    }
  }
}

// ---------------- output projection GEMM (f32 out, [M,N]) ----------------
__global__ __launch_bounds__(256) void gemmo_kernel(const u16* __restrict__ A,
                                                    const u16* __restrict__ Bw,
                                                    const float* __restrict__ bias,
                                                    float* __restrict__ Cout) {
  constexpr int K = 1024, N = 1024, BK = 32;
  __shared__ u16 As[128 * BK];
  __shared__ u16 Bs[128 * BK];
  const int t = threadIdx.x;
  const int w = t >> 6, l = t & 63;
  const int lr = l & 15, lh = l >> 4;
  const int m0 = blockIdx.y * 128, n0 = blockIdx.x * 128;
  const int wr = w >> 1, wc = w & 1;
  f32x4 acc[4][4] = {};

  const int row_s = t >> 2, k8 = (t & 3) << 3;
  const u16* ga = A + (size_t)(m0 + row_s) * K + k8;
  const u16* gb = Bw + (size_t)(n0 + row_s) * K + k8;

  for (int kt = 0; kt < K; kt += BK) {
    GLOAD_LDS(ga + kt, As + t * 8);
    GLOAD_LDS(ga + (size_t)64 * K + kt, As + 2048 + t * 8);
    GLOAD_LDS(gb + kt, Bs + t * 8);
    GLOAD_LDS(gb + (size_t)64 * K + kt, Bs + 2048 + t * 8);
    __syncthreads();
    bf16x8 af[4], bfr[4];
#pragma unroll
    for (int mi = 0; mi < 4; ++mi)
      af[mi] = *(const bf16x8*)(As + (wr * 64 + mi * 16 + lr) * BK + lh * 8);
#pragma unroll
    for (int ni = 0; ni < 4; ++ni)
      bfr[ni] = *(const bf16x8*)(Bs + (wc * 64 + ni * 16 + lr) * BK + lh * 8);
#pragma unroll
    for (int mi = 0; mi < 4; ++mi)
#pragma unroll
      for (int ni = 0; ni < 4; ++ni)
        acc[mi][ni] = mfma16(af[mi], bfr[ni], acc[mi][ni]);
    __syncthreads();
  }

#pragma unroll
  for (int mi = 0; mi < 4; ++mi) {
#pragma unroll
    for (int ni = 0; ni < 4; ++ni) {
      int col = n0 + wc * 64 + ni * 16 + lr;
      float bc = bias[col];
#pragma unroll
      for (int r = 0; r < 4; ++r) {
        int rowg = m0 + wr * 64 + mi * 16 + lh * 4 + r;
        Cout[(size_t)rowg * N + col] = acc[mi][ni][r] + bc;
      }
    }
  }
}

// ---------------- fused attention v5: 32-row q-tile -------------------------
// 2048 blocks (32 q-tiles x 64 bh). Two q-row groups per block:
//   group A rows q0+lr, group B rows q0+16+lr  (lane lr = l&15, lh = l>>4).
// Energy: swapped QK^T; each K/Ks register load feeds BOTH groups (8 MFMA per
// 4 loads) -> K/Ks load instrs + wave count halve vs 16-row tile.
// Energies -> 64KB bf16 E tile (swizzled 16B granule, rows 0..31).
// Softmax: wave w owns rows w*8..w*8+7; the WHOLE row is in-wave (6 shfl,
// exact, no cross-wave stage); emits coalesced CACHED f32 P stores inline.
// PV: V-frags shared across both groups; bf16 A-frags from E.
__global__ __launch_bounds__(256, 2) void attn5_kernel(const u16* __restrict__ Qh,
                                                       const u16* __restrict__ Kh,
                                                       const u16* __restrict__ Qsh,
                                                       const u16* __restrict__ Ksh,
                                                       const u16* __restrict__ Vth,
                                                       const uint32_t* __restrict__ mbits,
                                                       float* __restrict__ Pout,
                                                       u16* __restrict__ ctx) {
  __shared__ __align__(16) u16 E[32 * 1024]; // 64 KB bf16
  const int t = threadIdx.x, w = t >> 6, l = t & 63;
  const int lr = l & 15, lh = l >> 4;
  // XCD-aware remap: 32 q-tiles of one head stay on one XCD
  int lid = blockIdx.y * 32 + blockIdx.x;
  int xcd = lid & 7, j = lid >> 3;
  int bh = xcd * 8 + (j >> 5);
  int q0 = (j & 31) << 5;
  const int b = bh >> 4, h = bh & 15;
  const size_t hoff = (size_t)bh * Sc * HDc;

  // ---- Q fragments, both groups ----
  const u16* QpA = Qh + hoff + (size_t)(q0 + lr) * HDc + lh * 8;
  const u16* QspA = Qsh + hoff + (size_t)(q0 + lr) * HDc + lh * 8;
  bf16x8 qfA0 = *(const bf16x8*)QpA, qfA1 = *(const bf16x8*)(QpA + 32);
  bf16x8 sfA0 = *(const bf16x8*)QspA, sfA1 = *(const bf16x8*)(QspA + 32);
  bf16x8 qfB0 = *(const bf16x8*)(QpA + 16 * HDc), qfB1 = *(const bf16x8*)(QpA + 16 * HDc + 32);
  bf16x8 sfB0 = *(const bf16x8*)(QspA + 16 * HDc), sfB1 = *(const bf16x8*)(QspA + 16 * HDc + 32);

  // ---- mask words (rows q0+lr and q0+16+lr, window [w*256,(w+1)*256)) ----
  uint32_t mwA[8], mwB[8];
  {
    const uint32_t* mA = mbits + ((size_t)b * Sc + q0 + lr) * 32 + w * 8;
    *(uint4*)&mwA[0] = *(const uint4*)mA;
    *(uint4*)&mwA[4] = *(const uint4*)(mA + 4);
    const uint32_t* mB = mA + 16 * 32;
    *(uint4*)&mwB[0] = *(const uint4*)mB;
    *(uint4*)&mwB[4] = *(const uint4*)(mB + 4);
  }

  // ---- energy: wave w covers k in [w*256,(w+1)*256), depth-2 K prefetch ----
  const u16* Kbase = Kh + hoff + (size_t)((w << 8) + lr) * HDc + lh * 8;
  const u16* Ksbase = Ksh + hoff + (size_t)((w << 8) + lr) * HDc + lh * 8;

  bf16x8 ka[2], kb[2], sa[2], sb[2];
#define LOADK(slot, it) do { \
    const u16* Kp_ = Kbase + (it) * (16 * HDc); \
    const u16* Sp_ = Ksbase + (it) * (16 * HDc); \
    ka[slot] = *(const bf16x8*)Kp_;  kb[slot] = *(const bf16x8*)(Kp_ + 32); \
    sa[slot] = *(const bf16x8*)Sp_;  sb[slot] = *(const bf16x8*)(Sp_ + 32); } while (0)

  LOADK(0, 0); LOADK(1, 1);

#pragma unroll
  for (int kt = 0; kt < 16; ++kt) {
    const int s = kt & 1;
    f32x4 eA = {}, esA = {}, eB = {}, esB = {};
    eA = mfma16(ka[s], qfA0, eA);
    eA = mfma16(kb[s], qfA1, eA);
    esA = mfma16(sa[s], sfA0, esA);
    esA = mfma16(sb[s], sfA1, esA);
    eB = mfma16(ka[s], qfB0, eB);
    eB = mfma16(kb[s], qfB1, eB);
    esB = mfma16(sa[s], sfB0, esB);
    esB = mfma16(sb[s], sfB1, esB);
    if (kt + 2 < 16) LOADK(s, kt + 2);
    const int sh = ((kt & 1) << 4) + (lh << 2);
    const int kb16 = (w << 8) + (kt << 4) + (lh << 2);
    const int sphys = ((((kb16 >> 3) ^ (lr & 7)) << 3) | (kb16 & 7));
    {
      uint32_t md = mwA[kt >> 1];
      ushort4 wb;
      wb.x = f2bf(((md >> (sh + 0)) & 1u ? esA[0] : eA[0]) * 0.125f);
      wb.y = f2bf(((md >> (sh + 1)) & 1u ? esA[1] : eA[1]) * 0.125f);
      wb.z = f2bf(((md >> (sh + 2)) & 1u ? esA[2] : eA[2]) * 0.125f);
      wb.w = f2bf(((md >> (sh + 3)) & 1u ? esA[3] : eA[3]) * 0.125f);
      *(ushort4*)&E[(lr << 10) + sphys] = wb;
    }
    {
      uint32_t md = mwB[kt >> 1];
      ushort4 wb;
      wb.x = f2bf(((md >> (sh + 0)) & 1u ? esB[0] : eB[0]) * 0.125f);
      wb.y = f2bf(((md >> (sh + 1)) & 1u ? esB[1] : eB[1]) * 0.125f);
      wb.z = f2bf(((md >> (sh + 2)) & 1u ? esB[2] : eB[2]) * 0.125f);
      wb.w = f2bf(((md >> (sh + 3)) & 1u ? esB[3] : eB[3]) * 0.125f);
      *(ushort4*)&E[((lr + 16) << 10) + sphys] = wb;
    }
  }
#undef LOADK
  __syncthreads();

  // ---- softmax: wave w owns rows w*8..w*8+7 (full row in-wave, exact) ----
  // lane l covers k = j*256 + l*4 (j=0..3); coalesced f32 P store inline.
  float* Pb = Pout + ((size_t)bh * Sc + q0) * Sc;
#pragma unroll
  for (int r8 = 0; r8 < 8; ++r8) {
    const int row = (w << 3) + r8;
    const int sw = row & 7;
    float v[4][4];
#pragma unroll
    for (int jj = 0; jj < 4; ++jj) {
      int k = (jj << 8) + (l << 2);
      ushort4 raw = *(const ushort4*)&E[(row << 10) + ((((k >> 3) ^ sw) << 3) | (k & 7))];
      v[jj][0] = bf2f(raw.x); v[jj][1] = bf2f(raw.y);
      v[jj][2] = bf2f(raw.z); v[jj][3] = bf2f(raw.w);
    }
    float m = -1e30f;
#pragma unroll
    for (int jj = 0; jj < 4; ++jj)
      m = fmaxf(m, fmaxf(fmaxf(v[jj][0], v[jj][1]), fmaxf(v[jj][2], v[jj][3])));
#pragma unroll
    for (int off = 1; off < 64; off <<= 1) m = fmaxf(m, __shfl_xor(m, off));
    float sum = 0.f;
#pragma unroll
    for (int jj = 0; jj < 4; ++jj)
#pragma unroll
      for (int i = 0; i < 4; ++i) { float tt = __expf(v[jj][i] - m); v[jj][i] = tt; sum += tt; }
#pragma unroll
    for (int off = 1; off < 64; off <<= 1) sum += __shfl_xor(sum, off);
    const float inv = 1.f / sum;
#pragma unroll
    for (int jj = 0; jj < 4; ++jj) {
      int k = (jj << 8) + (l << 2);
      f32x4 pv = { v[jj][0] * inv, v[jj][1] * inv, v[jj][2] * inv, v[jj][3] * inv };
      *(f32x4*)(Pb + (size_t)row * Sc + k) = pv;   // cached, 1KB/wave-instr
      ushort4 wb;
      wb.x = f2bf(pv[0]); wb.y = f2bf(pv[1]); wb.z = f2bf(pv[2]); wb.w = f2bf(pv[3]);
      *(ushort4*)&E[(row << 10) + ((((k >> 3) ^ sw) << 3) | (k & 7))] = wb;
    }
  }

  // ---- V prefetch (depth-2) before the barrier; shared by both groups ----
  const u16* Vbp = Vth + ((size_t)bh * HDc + (w << 4) + lr) * Sc + lh * 8;
  bf16x8 va[2], vb[2];
#define LOADV(slot, it) do { \
    va[slot] = *(const bf16x8*)(Vbp + (it) * 64); \
    vb[slot] = *(const bf16x8*)(Vbp + (it) * 64 + 32); } while (0)
  LOADV(0, 0); LOADV(1, 1);

  __syncthreads();

  // ---- PV: wave w -> d-cols [w*16,+16); both q-groups share V frags ----
  const int swp = lr & 7;
  f32x4 accA0 = {}, accA1 = {}, accB0 = {}, accB1 = {};
#pragma unroll
  for (int it = 0; it < 16; ++it) {
    const int s = it & 1;
    int ka16 = (it << 6) + (lh << 3);
    int offL = (((ka16 >> 3) ^ swp) << 3);
    int offH = ((((ka16 + 32) >> 3) ^ swp) << 3);
    bf16x8 aA0 = *(const bf16x8*)&E[(lr << 10) + offL];
    bf16x8 aA1 = *(const bf16x8*)&E[(lr << 10) + offH];
    bf16x8 aB0 = *(const bf16x8*)&E[((lr + 16) << 10) + offL];
    bf16x8 aB1 = *(const bf16x8*)&E[((lr + 16) << 10) + offH];
    accA0 = mfma16(aA0, va[s], accA0);
    accA1 = mfma16(aA1, vb[s], accA1);
    accB0 = mfma16(aB0, va[s], accB0);
    accB1 = mfma16(aB1, vb[s], accB1);
    if (it + 2 < 16) LOADV(s, it + 2);
  }
#undef LOADV
  f32x4 accA = accA0 + accA1;
  f32x4 accB = accB0 + accB1;
#pragma unroll
  for (int r = 0; r < 4; ++r) {
    int rowA = q0 + (lh << 2) + r;
    ctx[((size_t)b * Sc + rowA) * Hc + (h << 6) + (w << 4) + lr] = f2bf(accA[r]);
    int rowB = rowA + 16;
    ctx[((size_t)b * Sc + rowB) * Hc + (h << 6) + (w << 4) + lr] = f2bf(accB[r]);
  }
}

extern "C" void kernel_launch(void* const* d_in, const int* in_sizes, int n_in,
                              void* d_out, int out_size, void* d_ws, size_t ws_size,
                              hipStream_t stream) {
  const float* fin[5] = { (const float*)d_in[0], (const float*)d_in[1], (const float*)d_in[2],
                          (const float*)d_in[3], (const float*)d_in[4] };
  const int* mask = (const int*)d_in[5];
  const float* W[6] = { (const float*)d_in[6], (const float*)d_in[8], (const float*)d_in[10],
                        (const float*)d_in[12], (const float*)d_in[14], (const float*)d_in[16] };
  const float* bias[6] = { (const float*)d_in[7], (const float*)d_in[9], (const float*)d_in[11],
                           (const float*)d_in[13], (const float*)d_in[15], (const float*)d_in[17] };

  float* out_x = (float*)d_out;
  float* out_attn = out_x + (size_t)Bc * Sc * Hc;

  const size_t NE = (size_t)Bc * Sc * Hc; // 4M elems
  const size_t NW = (size_t)Hc * Hc;      // 1M elems
  u16* p = (u16*)d_ws;
  u16* xin[5]; for (int i = 0; i < 5; ++i) { xin[i] = p; p += NE; }
  u16* wbf[6]; for (int i = 0; i < 6; ++i) { wbf[i] = p; p += NW; }
  u16* Qh  = p; p += NE;
  u16* Kh  = p; p += NE;
  u16* Qsh = p; p += NE;
  u16* Ksh = p; p += NE;
  u16* Vth = p; p += NE;
  u16* ctx = p; p += NE;
  uint32_t* mbits = (uint32_t*)xin[0]; // reused after proj5

  {
    CV a{};
    for (int i = 0; i < 5; ++i) { a.in[i] = fin[i]; a.out[i] = xin[i]; }
    cvtN_kernel<<<dim3((int)(NE / 8 / 256), 1, 5), 256, 0, stream>>>(a, (int)(NE / 8));
  }
  {
    CV a{};
    for (int i = 0; i < 6; ++i) { a.in[i] = W[i]; a.out[i] = wbf[i]; }
    cvtN_kernel<<<dim3((int)(NW / 8 / 256), 1, 6), 256, 0, stream>>>(a, (int)(NW / 8));
  }

  P5 args;
  u16* projout[5] = { Qh, Kh, Qsh, Ksh, Vth };
  for (int i = 0; i < 5; ++i) { args.A[i] = xin[i]; args.W[i] = wbf[i]; args.b[i] = bias[i]; args.o[i] = projout[i]; }
  proj5_kernel<<<dim3(Hc / 128, Mrows / 128, 5), 256, 0, stream>>>(args);

  maskpack_kernel<<<(int)((size_t)Bc * Sc * Sc / 32 / 256), 256, 0, stream>>>(mask, mbits);

  attn5_kernel<<<dim3(Sc / 32, Bc * NHc), 256, 0, stream>>>(Qh, Kh, Qsh, Ksh, Vth, mbits, out_attn, ctx);

  gemmo_kernel<<<dim3(Hc / 128, Mrows / 128), 256, 0, stream>>>(ctx, wbf[5], bias[5], out_x);
}